// Round 7
// baseline (165.459 us; speedup 1.0000x reference)
//
#include <hip/hip_runtime.h>

// RankingLoss: B=16384 rows, D=1024 fp32, C=14 int32 labels -> scalar fp32.
//
// R7: A/B on nontemporal (dropped — zero-duplication makes L2 churn moot,
// and nt may suppress L3 allocation, forcing HBM re-fetch of the ~half-
// L3-resident inputs) + 16-row blocks to halve the external halo.
//
// Block = 16 rows = two 8-row groups; each group served by 2 waves, one
// per D-half. Wave: 8 rows x 8 chunk-lanes, 16 iters of 16B/lane loads
// (128B line-exact per row). Imposter row r+1 via shfl_down(.,8); the
// boundary row (row_off==7) loads its halo directly — group 0's halo is
// group 1's primary (L2 hit), only group 1's halo (row r0+16) is external
// -> ~142.5 MB logical, each HBM line fetched ~once.
// Margins preloaded on threads 0..15 before the main loop.

constexpr int D   = 1024;
constexpr int C   = 14;
constexpr int RPB = 16;           // rows per block (2 groups of 8)
constexpr int CPR = D / 4;        // 256 float4 chunks per row

typedef float f4 __attribute__((ext_vector_type(4)));

__device__ __forceinline__ float dot4(const f4 x, const f4 y) {
    return x.x * y.x + x.y * y.y + x.z * y.z + x.w * y.w;
}

__device__ __forceinline__ f4 shfl_down4(const f4 v) {
    f4 r;
    r.x = __shfl_down(v.x, 8, 64);
    r.y = __shfl_down(v.y, 8, 64);
    r.z = __shfl_down(v.z, 8, 64);
    r.w = __shfl_down(v.w, 8, 64);
    return r;
}

__global__ __launch_bounds__(256) void rank_phase1(
    const float* __restrict__ zi, const float* __restrict__ zt,
    const int* __restrict__ labels, float* __restrict__ partial, int B)
{
    const int t    = threadIdx.x;
    const int wave = t >> 6;
    const int lane = t & 63;
    const int r0   = blockIdx.x * RPB;
    const int M    = B - 1;               // B is a power of two

    const int g  = wave >> 1;             // row group 0/1 (rows r0+8g..+7)
    const int h  = wave & 1;              // D-half 0/1

    const int row_off = lane >> 3;        // [0,8)
    const int cl      = lane & 7;         // chunk lane [0,8)
    const int row     = r0 + 8 * g + row_off;       // < B always
    const int hrow    = (r0 + 8 * g + 8) & M;       // group halo row

    // Margin preload: threads 0..15 handle output rows r0..r0+15.
    float margin = 0.f;
    if (t < RPB) {
        const int ra = r0 + t;
        const int rb = (ra + 1) & M;
        const int2* La = (const int2*)(labels + (size_t)ra * C);
        const int2* Lb = (const int2*)(labels + (size_t)rb * C);
        int dv = 0, nv = 0;
        #pragma unroll
        for (int q = 0; q < C / 2; ++q) { // binary labels
            const int2 x = La[q];
            const int2 y = Lb[q];
            dv += (x.x ^ y.x) + (x.y ^ y.y);
            nv += (x.x | y.x) + (x.y | y.y);
        }
        margin = (dv == 0) ? 0.f : fmaxf(0.5f, (float)dv / (float)nv);
    }

    const f4* ZI = (const f4*)zi;
    const f4* ZT = (const f4*)zt;
    const int cb = h * (CPR / 2);         // D-half base: 0 or 128

    float p = 0.f, ii = 0.f, it = 0.f;

    #pragma unroll
    for (int i = 0; i < CPR / 2 / 8; ++i) {     // 16 iterations
        const int c = cb + 8 * i + cl;
        const f4 a = ZI[(size_t)row * CPR + c];
        const f4 b = ZT[(size_t)row * CPR + c];

        f4 ha, hb;
        if (row_off == 7) {               // boundary: fetch group halo row
            ha = ZI[(size_t)hrow * CPR + c];
            hb = ZT[(size_t)hrow * CPR + c];
        }

        f4 aN = shfl_down4(a);            // row r+1, same chunk (lane+8)
        f4 bN = shfl_down4(b);
        if (row_off == 7) { aN = ha; bN = hb; }

        p  += dot4(a,  b);                // paired   dot(zi[r],  zt[r])
        ii += dot4(aN, b);                // imp_img  dot(zi[r+1],zt[r])
        it += dot4(bN, a);                // imp_txt  dot(zt[r+1],zi[r])
    }

    // Reduce across the 8 chunk lanes of each row group.
    #pragma unroll
    for (int off = 1; off < 8; off <<= 1) {
        p  += __shfl_xor(p,  off, 64);
        ii += __shfl_xor(ii, off, 64);
        it += __shfl_xor(it, off, 64);
    }

    __shared__ float sm[4][8][3];         // [wave][row_off][p,ii,it]
    if (cl == 0) {
        sm[wave][row_off][0] = p;
        sm[wave][row_off][1] = ii;
        sm[wave][row_off][2] = it;
    }
    __syncthreads();

    if (t < RPB) {                        // lanes 0..15 of wave 0
        const int gg = t >> 3;            // row group of output row t
        const int lr = t & 7;
        // Sum the two D-half waves of this group.
        const float ps = sm[2 * gg][lr][0] + sm[2 * gg + 1][lr][0];
        const float is = sm[2 * gg][lr][1] + sm[2 * gg + 1][lr][1];
        const float ts = sm[2 * gg][lr][2] + sm[2 * gg + 1][lr][2];
        float v = fmaxf(is - ps + margin, 0.f)
                + fmaxf(ts - ps + margin, 0.f);
        #pragma unroll
        for (int off = 1; off < RPB; off <<= 1)   // 16 active lanes
            v += __shfl_xor(v, off, 64);
        if (t == 0) partial[blockIdx.x] = v;
    }
}

__global__ __launch_bounds__(256) void rank_phase2(
    const float* __restrict__ partial, float* __restrict__ out,
    int npart, float invB)
{
    float s = 0.f;
    for (int i = threadIdx.x; i < npart; i += 256) s += partial[i];
    #pragma unroll
    for (int off = 32; off > 0; off >>= 1) s += __shfl_down(s, off, 64);
    __shared__ float sm[4];
    if ((threadIdx.x & 63) == 0) sm[threadIdx.x >> 6] = s;
    __syncthreads();
    if (threadIdx.x == 0)
        out[0] = (sm[0] + sm[1] + sm[2] + sm[3]) * invB;
}

extern "C" void kernel_launch(void* const* d_in, const int* in_sizes, int n_in,
                              void* d_out, int out_size, void* d_ws, size_t ws_size,
                              hipStream_t stream) {
    const float* zi     = (const float*)d_in[0];
    const float* zt     = (const float*)d_in[1];
    const int*   labels = (const int*)d_in[2];
    float*       out    = (float*)d_out;
    float*       ws     = (float*)d_ws;

    const int B      = in_sizes[0] / D;  // 16384
    const int blocks = B / RPB;          // 1024 -> 4 blocks/CU

    rank_phase1<<<blocks, 256, 0, stream>>>(zi, zt, labels, ws, B);
    rank_phase2<<<1, 256, 0, stream>>>(ws, out, blocks, 1.0f / (float)B);
}